// Round 13
// baseline (1125.646 us; speedup 1.0000x reference)
//
#include <hip/hip_runtime.h>

#define HID_ 1000
#define NB 256
#define TT 49
#define DIN 192
#define NPAD 1024
#define M_ALL (TT * 256)  // 12544

typedef _Float16 f16;
typedef _Float16 f16x4 __attribute__((ext_vector_type(4)));
typedef _Float16 f16x8 __attribute__((ext_vector_type(8)));
typedef float f32x4 __attribute__((ext_vector_type(4)));
typedef const __attribute__((address_space(1))) unsigned int* gas_u32;
typedef __attribute__((address_space(3))) unsigned int* las_u32;

__device__ __forceinline__ float sigmf_(float x) {
    return 1.0f / (1.0f + __expf(-x));
}
__device__ __forceinline__ float tanhf_(float x) {
    float ax = fabsf(x);
    float e = __expf(-2.0f * ax);
    float t = (1.0f - e) / (1.0f + e);
    return copysignf(t, x);
}

// Vectorized weight convert: fp32 [4*HID_][K] -> f16 [4][1024][KPADv], zero-pad.
__global__ __launch_bounds__(256) void conv_weight_v(
    const float* __restrict__ src, f16* __restrict__ dst, int K, int KPADv, int total8) {
    int idx = blockIdx.x * blockDim.x + threadIdx.x;
    if (idx >= total8) return;
    const int kpw = KPADv >> 3;
    const int kp = (idx % kpw) << 3;
    const int rest = idx / kpw;          // g*1024 + np
    const int np = rest & 1023;
    const int g = rest >> 10;
    f16x8 v = {};
    if (np < HID_ && kp < K) {
        const float* sp = src + (size_t)(g * HID_ + np) * K + kp;
        float4 a = *(const float4*)sp;
        float4 b = *(const float4*)(sp + 4);
        v[0] = (f16)a.x; v[1] = (f16)a.y; v[2] = (f16)a.z; v[3] = (f16)a.w;
        v[4] = (f16)b.x; v[5] = (f16)b.y; v[6] = (f16)b.z; v[7] = (f16)b.w;
    }
    *(f16x8*)(dst + (size_t)rest * KPADv + kp) = v;
}

// Vectorized enc_in transpose-convert: [B][T][D] fp32 -> [T][B][D] f16.
__global__ __launch_bounds__(256) void conv_x_v(
    const float* __restrict__ src, f16* __restrict__ dst, int total8) {
    int idx = blockIdx.x * blockDim.x + threadIdx.x;
    if (idx >= total8) return;
    const int kp = (idx % (DIN / 8)) << 3;
    const int rest = idx / (DIN / 8);    // t*NB + b
    const int b = rest & 255;
    const int t = rest >> 8;
    const float* sp = src + ((size_t)b * TT + t) * DIN + kp;
    float4 a = *(const float4*)sp;
    float4 c = *(const float4*)(sp + 4);
    f16x8 v;
    v[0] = (f16)a.x; v[1] = (f16)a.y; v[2] = (f16)a.z; v[3] = (f16)a.w;
    v[4] = (f16)c.x; v[5] = (f16)c.y; v[6] = (f16)c.z; v[7] = (f16)c.w;
    *(f16x8*)(dst + (size_t)rest * DIN + kp) = v;
}

// bias_c[4][NPAD] fp32 = b_ih + b_hh (zero-padded)
__global__ void conv_bias(const float* __restrict__ bih, const float* __restrict__ bhh,
                          float* __restrict__ dst) {
    int idx = blockIdx.x * blockDim.x + threadIdx.x;
    if (idx < 4 * NPAD) {
        int np = idx & (NPAD - 1);
        int g = idx >> 10;
        float v = 0.0f;
        if (np < HID_) v = bih[g * HID_ + np] + bhh[g * HID_ + np];
        dst[idx] = v;
    }
}

// pre2 = A @ W^T + bias, stored in the 16-row-chain fragment order:
// pre2[(((t*16+ch)*32+jt)*4+g)*512 + (u*16+r)*8 + n*4 + q]   (f16)
// where ch = batch/16, rows within chain map as row = u*4+q, col = n*16+r.
__global__ __launch_bounds__(256) void input_gemm(
    const f16* __restrict__ A, int lda, int kiters,
    const f16* __restrict__ W, int ldw,
    const float* __restrict__ bias,
    f16* __restrict__ pre2) {
    __shared__ f16 As[128 * 64];
    __shared__ f16 Bs[128 * 64];
    const int id = blockIdx.x;
    const int sw = (id & 7) * (gridDim.x >> 3) + (id >> 3);  // XCD swizzle (3136%8==0)
    const int m0 = (sw >> 5) << 7;
    const int n0 = (sw & 31) << 7;
    const int w = threadIdx.x >> 6;
    const int lane = threadIdx.x & 63;
    const int r = lane & 15;
    const int u = lane >> 4;
    const int kb8 = u << 3;  // frag k-offset (elements)
    const int wm = (w >> 1) << 6, wn = (w & 1) << 6;
    const int strow = (w << 5) + (lane >> 3);  // + q*8
    const int stcol = (lane & 7) << 3;         // elements

    f32x4 acc[4][4];
#pragma unroll
    for (int i = 0; i < 4; i++)
#pragma unroll
        for (int j = 0; j < 4; j++) acc[i][j] = (f32x4){0.f, 0.f, 0.f, 0.f};

    for (int kt = 0; kt < kiters; kt++) {
        const int k0 = kt << 6;
#pragma unroll
        for (int q = 0; q < 4; q++) {
            const int row = strow + (q << 3);
            const int cbase = ((w << 5) + (q << 3)) << 6;  // wave-uniform chunk base (elems)
            const f16* ga = A + (size_t)(m0 + row) * lda + k0 + stcol;
            const f16* gb = W + (size_t)(n0 + row) * ldw + k0 + stcol;
            __builtin_amdgcn_global_load_lds((gas_u32)ga, (las_u32)(As + cbase), 16, 0, 0);
            __builtin_amdgcn_global_load_lds((gas_u32)gb, (las_u32)(Bs + cbase), 16, 0, 0);
        }
        __syncthreads();
#pragma unroll
        for (int ks = 0; ks < 2; ks++) {
            f16x8 av[4], bv[4];
#pragma unroll
            for (int i = 0; i < 4; i++)
                av[i] = *(const f16x8*)(As + ((wm + i * 16 + r) << 6) + (ks << 5) + kb8);
#pragma unroll
            for (int j = 0; j < 4; j++)
                bv[j] = *(const f16x8*)(Bs + ((wn + j * 16 + r) << 6) + (ks << 5) + kb8);
#pragma unroll
            for (int i = 0; i < 4; i++)
#pragma unroll
                for (int j = 0; j < 4; j++)
                    acc[i][j] = __builtin_amdgcn_mfma_f32_16x16x32_f16(av[i], bv[j], acc[i][j], 0, 0, 0);
        }
        __syncthreads();
    }

#pragma unroll
    for (int j = 0; j < 4; j++) {
        const int gcol = n0 + wn + j * 16 + r;
        const float bj = bias[gcol];
        const int g = gcol >> 10, cl = gcol & 1023;
        const int jt2 = cl >> 5, c = cl & 31;
        const int n2 = c >> 4, r2 = c & 15;
#pragma unroll
        for (int i = 0; i < 4; i++) {
            const int grow = m0 + wm + i * 16 + (u << 2);  // q=0 row
            const int t_ = grow >> 8;
            const int ch = (grow >> 4) & 15;
            f16x4 hv;
#pragma unroll
            for (int q = 0; q < 4; q++) hv[q] = (f16)(acc[i][j][q] + bj);
            *(f16x4*)(pre2 + ((((size_t)t_ * 16 + ch) * 32 + jt2) * 4 + g) * 512 +
                      (u * 16 + r2) * 8 + n2 * 4) = hv;
        }
    }
}

// Persistent per-layer recurrent kernel — DUAL-CHAIN latency hiding.
// 16 chains of 16 batches; wg (c = bid&7, jt = bid>>3) processes chains
// {2c, 2c+1}: per iteration, phase A (chain 2c, step t) then phase B
// (chain 2c+1, step t). Chain A's flag round-trip propagates during phase B
// (and vice versa) -> the LLC latency overlaps useful work instead of idle
// spin. Weights shared by both chains (same jt slice, wreg 128 VGPR).
// LDS: hA 32KB + hB 32KB + one reused pl 17KB. Sync/publish mechanics
// (relaxed AGENT atomics, first-touch reads, drain-then-signal) = r5-r12.
__global__ __launch_bounds__(512, 2) void rec_persist(
    const f16* __restrict__ Whh, const f16* __restrict__ pre2,
    f16* __restrict__ hall, float* __restrict__ outl,
    unsigned int* __restrict__ flags) {
    __shared__ __align__(16) char hA[16 * 2048];   // chain-A h tile (XOR-swizzled)
    __shared__ __align__(16) char hB[16 * 2048];   // chain-B h tile
    __shared__ float pl[2 * 4 * 16 * 34];          // [kh][gate][row][34] (reused A/B)
    const int bid = blockIdx.x;
    const int c = bid & 7;     // chain-pair group (XCD-local under round-robin)
    const int jt = bid >> 3;   // column tile 0..31
    const int chA = 2 * c, chB = 2 * c + 1;
    const int jc0 = jt << 5;
    const int tid = threadIdx.x;
    const int w = tid >> 6;
    const int g = w >> 1;      // gate 0..3
    const int kh = w & 1;      // K-half
    const int lane = tid & 63;
    const int r = lane & 15;
    const int u = lane >> 4;
    const int kbb = u << 4;    // bytes
    const int swz = (r & 7) << 4;

    // load this wave's K-half of the weights into registers (once per layer)
    f16x8 wreg[2][16];
#pragma unroll
    for (int n = 0; n < 2; n++) {
        const f16* wp = Whh + ((size_t)(g * NPAD + jc0 + n * 16 + r)) * NPAD + (kh << 9) + (u << 3);
#pragma unroll
        for (int ks = 0; ks < 16; ks++) wreg[n][ks] = *(const f16x8*)(wp + ks * 32);
    }

    const int eb = tid >> 5;         // epilogue row 0..15
    const int ej = tid & 31;         // epilogue col 0..31 (1 col/thread)
    float cvA = 0.f, cvB = 0.f;
    unsigned int* flA = flags + chA * 64;
    unsigned int* flB = flags + chB * 64;
    const size_t preblkA = (((size_t)chA * 32 + jt) * 4 + g) * 512 + lane * 8;
    const size_t preblkB = (((size_t)chB * 32 + jt) * 4 + g) * 512 + lane * 8;

    auto LOADP = [&](int tindex, size_t preblk, f16x8& pc) {
        if (kh == 0) pc = *(const f16x8*)(pre2 + (size_t)tindex * 1048576 + preblk);
    };

    // one chain step: wait -> stage -> mfma -> pl -> epi -> publish -> signal
    auto PHASE = [&](int t, int ch, char* hX, unsigned int* fl, f16x8& pc, float& cv) {
        if (t > 0) {
            while (__hip_atomic_load(fl + (t - 1), __ATOMIC_RELAXED,
                                     __HIP_MEMORY_SCOPE_AGENT) < 32u) {}
            asm volatile("" ::: "memory");
            // stage h[t-1] rows ch*16..+16 -> hX (XOR-swizzled rows), 32KB
            const char* hread = (const char*)(hall + (size_t)(t - 1) * NB * NPAD +
                                              (size_t)ch * 16 * NPAD);
#pragma unroll
            for (int i = 0; i < 4; i++) {
                int c2 = tid + (i << 9);
                int row = c2 >> 7;
                int cb = (c2 & 127) << 4;
                f16x8 v = *(const f16x8*)(hread + (size_t)row * 2048 + cb);
                *(f16x8*)(hX + row * 2048 + (cb ^ ((row & 7) << 4))) = v;
            }
        }
        __syncthreads();  // P1: h tile staged (also orders pl reuse vs prior epi)

        f32x4 acc[2];  // [n]
#pragma unroll
        for (int n = 0; n < 2; n++)
#pragma unroll
            for (int q = 0; q < 4; q++)
                acc[n][q] = (kh == 0) ? (float)pc[n * 4 + q] : 0.f;

        if (t > 0) {
#pragma unroll
            for (int ks = 0; ks < 16; ks++) {
                const int ksg = (kh << 4) + ks;
                f16x8 a0 = *(const f16x8*)(hX + r * 2048 + ((ksg * 64 + kbb) ^ swz));
                acc[0] = __builtin_amdgcn_mfma_f32_16x16x32_f16(a0, wreg[0][ks], acc[0], 0, 0, 0);
                acc[1] = __builtin_amdgcn_mfma_f32_16x16x32_f16(a0, wreg[1][ks], acc[1], 0, 0, 0);
            }
        }
        // write this K-half's partials (own region, no RMW)
#pragma unroll
        for (int n = 0; n < 2; n++)
#pragma unroll
            for (int q = 0; q < 4; q++)
                pl[((kh * 4 + g) * 16 + u * 4 + q) * 34 + n * 16 + r] = acc[n][q];
        __syncthreads();  // P2: partials ready

        // cell update: thread -> (eb, ej), 1 col
        float gv[4];
#pragma unroll
        for (int gate = 0; gate < 4; gate++)
            gv[gate] = pl[((0 * 4 + gate) * 16 + eb) * 34 + ej] +
                       pl[((1 * 4 + gate) * 16 + eb) * 34 + ej];
        float cn = sigmf_(gv[1]) * cv + sigmf_(gv[0]) * tanhf_(gv[2]);
        float hv = sigmf_(gv[3]) * tanhf_(cn);
        cv = cn;
        // publish h via relaxed AGENT atomic store (coherence point)
        {
            union { f16 h; unsigned short s; } cvt;
            cvt.h = (f16)hv;
            __hip_atomic_store(
                (unsigned short*)(hall + (size_t)t * NB * NPAD +
                                  (size_t)(ch * 16 + eb) * NPAD + jc0 + ej),
                cvt.s, __ATOMIC_RELAXED, __HIP_MEMORY_SCOPE_AGENT);
        }
        __syncthreads();  // P3: vmcnt drained -> h stores visible; pl reads done
        if (tid == 0)
            __hip_atomic_fetch_add(fl + t, 1u, __ATOMIC_RELAXED, __HIP_MEMORY_SCOPE_AGENT);
        // output store AFTER the signal
        const int col = jc0 + ej;
        if (col < HID_)
            outl[((size_t)(ch * 16 + eb) * TT + t) * HID_ + col] = hv;
    };

    f16x8 pcA = {}, pnA = {}, pcB = {}, pnB = {};
    LOADP(0, preblkA, pcA);
    LOADP(0, preblkB, pcB);
    for (int t = 0; t < TT; t += 2) {
        const int t1 = (t + 1 < TT) ? t + 1 : t;
        const int t2 = (t + 2 < TT) ? t + 2 : t;
        LOADP(t1, preblkA, pnA);
        LOADP(t1, preblkB, pnB);
        PHASE(t, chA, hA, flA, pcA, cvA);
        PHASE(t, chB, hB, flB, pcB, cvB);
        if (t + 1 < TT) {
            LOADP(t2, preblkA, pcA);
            LOADP(t2, preblkB, pcB);
            PHASE(t + 1, chA, hA, flA, pnA, cvA);
            PHASE(t + 1, chB, hB, flB, pnB, cvB);
        }
    }
}

extern "C" void kernel_launch(void* const* d_in, const int* in_sizes, int n_in,
                              void* d_out, int out_size, void* d_ws, size_t ws_size,
                              hipStream_t stream) {
    const float* enc_in = (const float*)d_in[0];
    const float* W_ih[3] = {(const float*)d_in[1], (const float*)d_in[5], (const float*)d_in[9]};
    const float* W_hh[3] = {(const float*)d_in[2], (const float*)d_in[6], (const float*)d_in[10]};
    const float* b_ih[3] = {(const float*)d_in[3], (const float*)d_in[7], (const float*)d_in[11]};
    const float* b_hh[3] = {(const float*)d_in[4], (const float*)d_in[8], (const float*)d_in[12]};
    float* out = (float*)d_out;

    char* ws = (char*)d_ws;
    size_t off = 0;
    auto alloc = [&](size_t bytes) {
        char* p = ws + off;
        off += (bytes + 255) & ~(size_t)255;
        return p;
    };
    f16* Wih_c[3];
    f16* Whh_c[3];
    Wih_c[0] = (f16*)alloc(4ull * NPAD * DIN * sizeof(f16));
    Whh_c[0] = (f16*)alloc(4ull * NPAD * NPAD * sizeof(f16));
    Wih_c[1] = (f16*)alloc(4ull * NPAD * NPAD * sizeof(f16));
    Whh_c[1] = (f16*)alloc(4ull * NPAD * NPAD * sizeof(f16));
    Wih_c[2] = (f16*)alloc(4ull * NPAD * NPAD * sizeof(f16));
    Whh_c[2] = (f16*)alloc(4ull * NPAD * NPAD * sizeof(f16));
    float* bias_c[3];
    for (int l = 0; l < 3; l++) bias_c[l] = (float*)alloc(4ull * NPAD * sizeof(float));
    f16* xbf = (f16*)alloc((size_t)TT * NB * DIN * sizeof(f16));
    f16* hall[3];
    for (int l = 0; l < 3; l++) hall[l] = (f16*)alloc((size_t)TT * NB * NPAD * sizeof(f16));
    f16* pre2 = (f16*)alloc((size_t)M_ALL * 4096 * sizeof(f16));
    // flags: [layer][chain 0..15][64 ints]
    const size_t fl_layer = 16 * 64;
    unsigned int* flags = (unsigned int*)alloc(3 * fl_layer * sizeof(unsigned int));

    hipMemsetAsync(flags, 0, 3 * fl_layer * sizeof(unsigned int), stream);

    {
        int t8_l0 = 4 * NPAD * DIN / 8;
        conv_weight_v<<<(t8_l0 + 255) / 256, 256, 0, stream>>>(W_ih[0], Wih_c[0], DIN, DIN, t8_l0);
        int t8 = 4 * NPAD * NPAD / 8;
        conv_weight_v<<<(t8 + 255) / 256, 256, 0, stream>>>(W_hh[0], Whh_c[0], HID_, NPAD, t8);
        conv_weight_v<<<(t8 + 255) / 256, 256, 0, stream>>>(W_ih[1], Wih_c[1], HID_, NPAD, t8);
        conv_weight_v<<<(t8 + 255) / 256, 256, 0, stream>>>(W_hh[1], Whh_c[1], HID_, NPAD, t8);
        conv_weight_v<<<(t8 + 255) / 256, 256, 0, stream>>>(W_ih[2], Wih_c[2], HID_, NPAD, t8);
        conv_weight_v<<<(t8 + 255) / 256, 256, 0, stream>>>(W_hh[2], Whh_c[2], HID_, NPAD, t8);
    }
    {
        int t8x = TT * NB * (DIN / 8);
        conv_x_v<<<(t8x + 255) / 256, 256, 0, stream>>>(enc_in, xbf, t8x);
    }
    for (int l = 0; l < 3; l++)
        conv_bias<<<(4 * NPAD + 255) / 256, 256, 0, stream>>>(b_ih[l], b_hh[l], bias_c[l]);

    for (int l = 0; l < 3; l++) {
        if (l == 0)
            input_gemm<<<3136, 256, 0, stream>>>(xbf, DIN, DIN / 64, Wih_c[0], DIN,
                                                 bias_c[0], pre2);
        else
            input_gemm<<<3136, 256, 0, stream>>>(hall[l - 1], NPAD, NPAD / 64, Wih_c[l], NPAD,
                                                 bias_c[l], pre2);
        rec_persist<<<256, 512, 0, stream>>>(
            Whh_c[l], pre2, hall[l], out + (size_t)l * NB * TT * HID_,
            flags + (size_t)l * fl_layer);
    }
}

// Round 14
// 1078.580 us; speedup vs baseline: 1.0436x; 1.0436x over previous
//
#include <hip/hip_runtime.h>

#define HID_ 1000
#define NB 256
#define TT 49
#define DIN 192
#define NPAD 1024
#define M_ALL (TT * 256)  // 12544

typedef _Float16 f16;
typedef _Float16 f16x4 __attribute__((ext_vector_type(4)));
typedef _Float16 f16x8 __attribute__((ext_vector_type(8)));
typedef float f32x4 __attribute__((ext_vector_type(4)));
typedef float f32x16 __attribute__((ext_vector_type(16)));
typedef const __attribute__((address_space(1))) unsigned int* gas_u32;
typedef __attribute__((address_space(3))) unsigned int* las_u32;

__device__ __forceinline__ float sigmf_(float x) {
    return 1.0f / (1.0f + __expf(-x));
}
__device__ __forceinline__ float tanhf_(float x) {
    float ax = fabsf(x);
    float e = __expf(-2.0f * ax);
    float t = (1.0f - e) / (1.0f + e);
    return copysignf(t, x);
}

// Vectorized weight convert: fp32 [4*HID_][K] -> f16 [4][1024][KPADv], zero-pad.
__global__ __launch_bounds__(256) void conv_weight_v(
    const float* __restrict__ src, f16* __restrict__ dst, int K, int KPADv, int total8) {
    int idx = blockIdx.x * blockDim.x + threadIdx.x;
    if (idx >= total8) return;
    const int kpw = KPADv >> 3;
    const int kp = (idx % kpw) << 3;
    const int rest = idx / kpw;          // g*1024 + np
    const int np = rest & 1023;
    const int g = rest >> 10;
    f16x8 v = {};
    if (np < HID_ && kp < K) {
        const float* sp = src + (size_t)(g * HID_ + np) * K + kp;
        float4 a = *(const float4*)sp;
        float4 b = *(const float4*)(sp + 4);
        v[0] = (f16)a.x; v[1] = (f16)a.y; v[2] = (f16)a.z; v[3] = (f16)a.w;
        v[4] = (f16)b.x; v[5] = (f16)b.y; v[6] = (f16)b.z; v[7] = (f16)b.w;
    }
    *(f16x8*)(dst + (size_t)rest * KPADv + kp) = v;
}

// Vectorized enc_in transpose-convert: [B][T][D] fp32 -> [T][B][D] f16.
__global__ __launch_bounds__(256) void conv_x_v(
    const float* __restrict__ src, f16* __restrict__ dst, int total8) {
    int idx = blockIdx.x * blockDim.x + threadIdx.x;
    if (idx >= total8) return;
    const int kp = (idx % (DIN / 8)) << 3;
    const int rest = idx / (DIN / 8);    // t*NB + b
    const int b = rest & 255;
    const int t = rest >> 8;
    const float* sp = src + ((size_t)b * TT + t) * DIN + kp;
    float4 a = *(const float4*)sp;
    float4 c = *(const float4*)(sp + 4);
    f16x8 v;
    v[0] = (f16)a.x; v[1] = (f16)a.y; v[2] = (f16)a.z; v[3] = (f16)a.w;
    v[4] = (f16)c.x; v[5] = (f16)c.y; v[6] = (f16)c.z; v[7] = (f16)c.w;
    *(f16x8*)(dst + (size_t)rest * DIN + kp) = v;
}

// bias_c[4][NPAD] fp32 = b_ih + b_hh (zero-padded)
__global__ void conv_bias(const float* __restrict__ bih, const float* __restrict__ bhh,
                          float* __restrict__ dst) {
    int idx = blockIdx.x * blockDim.x + threadIdx.x;
    if (idx < 4 * NPAD) {
        int np = idx & (NPAD - 1);
        int g = idx >> 10;
        float v = 0.0f;
        if (np < HID_) v = bih[g * HID_ + np] + bhh[g * HID_ + np];
        dst[idx] = v;
    }
}

// pre2 = A @ W^T + bias, stored in rec's 32x32-fragment order:
// element (batch row32, col32) of block (t,bt,jt,g) lives at
//   blk*1024 + lane*16 + reg,  lane = col32 + 32*((row32>>2)&1),
//   reg = (row32&3) + 4*(row32>>3)     [inverse of 32x32 C-layout]
__global__ __launch_bounds__(256) void input_gemm(
    const f16* __restrict__ A, int lda, int kiters,
    const f16* __restrict__ W, int ldw,
    const float* __restrict__ bias,
    f16* __restrict__ pre2) {
    __shared__ f16 As[128 * 64];
    __shared__ f16 Bs[128 * 64];
    const int id = blockIdx.x;
    const int sw = (id & 7) * (gridDim.x >> 3) + (id >> 3);  // XCD swizzle (3136%8==0)
    const int m0 = (sw >> 5) << 7;
    const int n0 = (sw & 31) << 7;
    const int w = threadIdx.x >> 6;
    const int lane = threadIdx.x & 63;
    const int r = lane & 15;
    const int u = lane >> 4;
    const int kb8 = u << 3;  // frag k-offset (elements)
    const int wm = (w >> 1) << 6, wn = (w & 1) << 6;
    const int strow = (w << 5) + (lane >> 3);  // + q*8
    const int stcol = (lane & 7) << 3;         // elements

    f32x4 acc[4][4];
#pragma unroll
    for (int i = 0; i < 4; i++)
#pragma unroll
        for (int j = 0; j < 4; j++) acc[i][j] = (f32x4){0.f, 0.f, 0.f, 0.f};

    for (int kt = 0; kt < kiters; kt++) {
        const int k0 = kt << 6;
#pragma unroll
        for (int q = 0; q < 4; q++) {
            const int row = strow + (q << 3);
            const int cbase = ((w << 5) + (q << 3)) << 6;  // wave-uniform chunk base (elems)
            const f16* ga = A + (size_t)(m0 + row) * lda + k0 + stcol;
            const f16* gb = W + (size_t)(n0 + row) * ldw + k0 + stcol;
            __builtin_amdgcn_global_load_lds((gas_u32)ga, (las_u32)(As + cbase), 16, 0, 0);
            __builtin_amdgcn_global_load_lds((gas_u32)gb, (las_u32)(Bs + cbase), 16, 0, 0);
        }
        __syncthreads();
#pragma unroll
        for (int ks = 0; ks < 2; ks++) {
            f16x8 av[4], bv[4];
#pragma unroll
            for (int i = 0; i < 4; i++)
                av[i] = *(const f16x8*)(As + ((wm + i * 16 + r) << 6) + (ks << 5) + kb8);
#pragma unroll
            for (int j = 0; j < 4; j++)
                bv[j] = *(const f16x8*)(Bs + ((wn + j * 16 + r) << 6) + (ks << 5) + kb8);
#pragma unroll
            for (int i = 0; i < 4; i++)
#pragma unroll
                for (int j = 0; j < 4; j++)
                    acc[i][j] = __builtin_amdgcn_mfma_f32_16x16x32_f16(av[i], bv[j], acc[i][j], 0, 0, 0);
        }
        __syncthreads();
    }

#pragma unroll
    for (int j = 0; j < 4; j++) {
        const int gcol = n0 + wn + j * 16 + r;
        const float bj = bias[gcol];
        const int g = gcol >> 10;
        const int jt2 = (gcol & 1023) >> 5;
        const int col32 = gcol & 31;
#pragma unroll
        for (int i = 0; i < 4; i++) {
            const int grow = m0 + wm + i * 16 + (u << 2);  // q=0 row
            const int t_ = grow >> 8;
            const int bt2 = (grow >> 5) & 7;
            // row32 = (i&1)*16 + u*4 + q ; lane2 = col32 + 32*(u&1)
            // reg   = q + 8*(i&1) + 4*(u>>1)   (q 0..3 contiguous)
            const int lane2 = col32 + ((u & 1) << 5);
            const int regbase = ((i & 1) << 3) + ((u >> 1) << 2);
            f16x4 hv;
#pragma unroll
            for (int q = 0; q < 4; q++) hv[q] = (f16)(acc[i][j][q] + bj);
            *(f16x4*)(pre2 + ((((size_t)t_ * 8 + bt2) * 32 + jt2) * 4 + g) * 1024 +
                      lane2 * 16 + regbase) = hv;
        }
    }
}

// Persistent per-layer recurrent kernel — r11 skeleton/sync, MFMA shape
// switched to 32x32x16: wave (g, kh) computes gate g's FULL 32x32 tile over
// K-half kh with ONE f16x8 A-frag per k-step -> LDS A-traffic halves
// (512 -> 256 KB/CU/step). Stage swizzle widened to 5 bits (row<<4): the
// 32-row A-read is conflict-free. Sync/publish mechanics = r5-r12 validated.
__global__ __launch_bounds__(512, 2) void rec_persist(
    const f16* __restrict__ Whh, const f16* __restrict__ pre2,
    f16* __restrict__ hall, float* __restrict__ outl,
    unsigned int* __restrict__ flags) {
    __shared__ __align__(16) char smem[64 * 1024];  // h tile [32 rows][2048B] XOR5-swizzled
    __shared__ float pl[2 * 4 * 32 * 34];           // [kh][gate][row][34] partials
    const int bid = blockIdx.x;
    const int bt = bid & 7;    // batch group (XCD-local under round-robin)
    const int jt = bid >> 3;   // column tile 0..31
    const int b0 = bt << 5;
    const int jc0 = jt << 5;
    const int tid = threadIdx.x;
    const int w = tid >> 6;
    const int g = w >> 1;      // gate 0..3
    const int kh = w & 1;      // K-half
    const int lane = tid & 63;
    const int row = lane & 31; // A row / B col within 32x32 tile
    const int kg = lane >> 5;  // k-group (0,1)

    // weights: gate g, cols jc0+row, K-half kh in B-fragment order -> 128 VGPR
    f16x8 wreg[32];
    {
        const f16* wp = Whh + ((size_t)(g * NPAD + jc0 + row)) * NPAD + (kh << 9) + (kg << 3);
#pragma unroll
        for (int ks = 0; ks < 32; ks++) wreg[ks] = *(const f16x8*)(wp + ks * 16);
    }

    const int eb = tid >> 4;          // epilogue batch row 0..31
    const int ej = (tid & 15) << 1;   // epilogue col pair
    float cv[2] = {0.f, 0.f};
    unsigned int* myflags = flags + bt * TT;
    const size_t preblk = ((((size_t)bt) * 32 + jt) * 4 + g) * 1024 + lane * 16;

    auto LOADP = [&](int tindex, f16x8& pa, f16x8& pb) {
        if (kh == 0) {
            const f16* pp = pre2 + (size_t)tindex * 8 * 32 * 4 * 1024 + preblk;
            pa = *(const f16x8*)pp;
            pb = *(const f16x8*)(pp + 8);
        }
    };

    auto STEP = [&](int t, f16x8& pc0, f16x8& pc1, f16x8& pn0, f16x8& pn1) {
        // prefetch next step's pre2 block (hides under spin + MFMA)
        LOADP(t + 1 < TT ? t + 1 : t, pn0, pn1);

        if (t > 0) {
            // wave-autonomous spin on the single group flag line
            while (__hip_atomic_load(myflags + (t - 1), __ATOMIC_RELAXED,
                                     __HIP_MEMORY_SCOPE_AGENT) < 32u) {}
            asm volatile("" ::: "memory");
            // stage h = hall[t-1] rows b0..b0+31 -> LDS (5-bit XOR rows)
            const f16* hread = hall + (size_t)(t - 1) * NB * NPAD;
#pragma unroll
            for (int i = 0; i < 8; i++) {
                int c = tid + (i << 9);
                int srow = c >> 7;
                int cb = (c & 127) << 4;
                f16x8 v = *(const f16x8*)(hread + (size_t)(b0 + srow) * NPAD + (cb >> 1));
                *(f16x8*)(smem + srow * 2048 + (cb ^ (srow << 4))) = v;
            }
        }
        __syncthreads();  // B1: h tile staged

        // acc init: kh=0 from pre2 fragment regs, kh=1 zero
        f32x16 acc;
#pragma unroll
        for (int reg = 0; reg < 16; reg++)
            acc[reg] = (kh == 0) ? (float)(reg < 8 ? pc0[reg] : pc1[reg - 8]) : 0.f;

        if (t > 0) {
#pragma unroll
            for (int ks = 0; ks < 32; ks++) {
                const int bc = (kh << 10) + ks * 32 + (kg << 4);  // byte col in row
                f16x8 a = *(const f16x8*)(smem + row * 2048 + (bc ^ (row << 4)));
                acc = __builtin_amdgcn_mfma_f32_32x32x16_f16(a, wreg[ks], acc, 0, 0, 0);
            }
        }

        // write this K-half's partials (own region, no RMW)
#pragma unroll
        for (int reg = 0; reg < 16; reg++) {
            const int prow = (reg & 3) + ((reg >> 2) << 3) + (kg << 2);
            pl[((kh * 4 + g) * 32 + prow) * 34 + row] = acc[reg];
        }
        __syncthreads();  // B2: partials ready

        // cell update: thread -> (eb, ej..ej+1); gate = kh0 + kh1 partials
        float hvv[2];
        {
            float gv[4][2];
#pragma unroll
            for (int gate = 0; gate < 4; gate++) {
                float2 p0 = *(const float2*)&pl[((0 * 4 + gate) * 32 + eb) * 34 + ej];
                float2 p1 = *(const float2*)&pl[((1 * 4 + gate) * 32 + eb) * 34 + ej];
                gv[gate][0] = p0.x + p1.x;
                gv[gate][1] = p0.y + p1.y;
            }
#pragma unroll
            for (int q = 0; q < 2; q++) {
                float cn = sigmf_(gv[1][q]) * cv[q] + sigmf_(gv[0][q]) * tanhf_(gv[2][q]);
                hvv[q] = sigmf_(gv[3][q]) * tanhf_(cn);
                cv[q] = cn;
            }
        }
        // publish h to hall[t] via relaxed AGENT atomic store (coherence point)
        {
            union { f16 h2[2]; unsigned uu; } cvt;
            cvt.h2[0] = (f16)hvv[0];
            cvt.h2[1] = (f16)hvv[1];
            __hip_atomic_store(
                (unsigned*)(hall + ((size_t)t * NB + b0 + eb) * NPAD + jc0 + ej), cvt.uu,
                __ATOMIC_RELAXED, __HIP_MEMORY_SCOPE_AGENT);
        }
        __syncthreads();  // B3: vmcnt drained -> h stores visible; pl reads done
        if (tid == 0)
            __hip_atomic_fetch_add(myflags + t, 1u, __ATOMIC_RELAXED, __HIP_MEMORY_SCOPE_AGENT);
        // output store AFTER the signal (nothing reads outl this dispatch)
        const int col = jc0 + ej;
        if (col < HID_) {
            *(float2*)(outl + ((size_t)(b0 + eb) * TT + t) * HID_ + col) =
                make_float2(hvv[0], hvv[1]);
        }
    };

    f16x8 pA0 = {}, pA1 = {}, pB0 = {}, pB1 = {};
    LOADP(0, pA0, pA1);
    for (int t = 0; t < TT; t += 2) {
        STEP(t, pA0, pA1, pB0, pB1);
        if (t + 1 < TT) STEP(t + 1, pB0, pB1, pA0, pA1);
    }
}

extern "C" void kernel_launch(void* const* d_in, const int* in_sizes, int n_in,
                              void* d_out, int out_size, void* d_ws, size_t ws_size,
                              hipStream_t stream) {
    const float* enc_in = (const float*)d_in[0];
    const float* W_ih[3] = {(const float*)d_in[1], (const float*)d_in[5], (const float*)d_in[9]};
    const float* W_hh[3] = {(const float*)d_in[2], (const float*)d_in[6], (const float*)d_in[10]};
    const float* b_ih[3] = {(const float*)d_in[3], (const float*)d_in[7], (const float*)d_in[11]};
    const float* b_hh[3] = {(const float*)d_in[4], (const float*)d_in[8], (const float*)d_in[12]};
    float* out = (float*)d_out;

    char* ws = (char*)d_ws;
    size_t off = 0;
    auto alloc = [&](size_t bytes) {
        char* p = ws + off;
        off += (bytes + 255) & ~(size_t)255;
        return p;
    };
    f16* Wih_c[3];
    f16* Whh_c[3];
    Wih_c[0] = (f16*)alloc(4ull * NPAD * DIN * sizeof(f16));
    Whh_c[0] = (f16*)alloc(4ull * NPAD * NPAD * sizeof(f16));
    Wih_c[1] = (f16*)alloc(4ull * NPAD * NPAD * sizeof(f16));
    Whh_c[1] = (f16*)alloc(4ull * NPAD * NPAD * sizeof(f16));
    Wih_c[2] = (f16*)alloc(4ull * NPAD * NPAD * sizeof(f16));
    Whh_c[2] = (f16*)alloc(4ull * NPAD * NPAD * sizeof(f16));
    float* bias_c[3];
    for (int l = 0; l < 3; l++) bias_c[l] = (float*)alloc(4ull * NPAD * sizeof(float));
    f16* xbf = (f16*)alloc((size_t)TT * NB * DIN * sizeof(f16));
    f16* hall[3];
    for (int l = 0; l < 3; l++) hall[l] = (f16*)alloc((size_t)TT * NB * NPAD * sizeof(f16));
    f16* pre2 = (f16*)alloc((size_t)M_ALL * 4096 * sizeof(f16));
    unsigned int* flags = (unsigned int*)alloc(3ull * 8 * TT * sizeof(unsigned int));

    hipMemsetAsync(flags, 0, 3ull * 8 * TT * sizeof(unsigned int), stream);

    {
        int t8_l0 = 4 * NPAD * DIN / 8;
        conv_weight_v<<<(t8_l0 + 255) / 256, 256, 0, stream>>>(W_ih[0], Wih_c[0], DIN, DIN, t8_l0);
        int t8 = 4 * NPAD * NPAD / 8;
        conv_weight_v<<<(t8 + 255) / 256, 256, 0, stream>>>(W_hh[0], Whh_c[0], HID_, NPAD, t8);
        conv_weight_v<<<(t8 + 255) / 256, 256, 0, stream>>>(W_ih[1], Wih_c[1], HID_, NPAD, t8);
        conv_weight_v<<<(t8 + 255) / 256, 256, 0, stream>>>(W_hh[1], Whh_c[1], HID_, NPAD, t8);
        conv_weight_v<<<(t8 + 255) / 256, 256, 0, stream>>>(W_ih[2], Wih_c[2], HID_, NPAD, t8);
        conv_weight_v<<<(t8 + 255) / 256, 256, 0, stream>>>(W_hh[2], Whh_c[2], HID_, NPAD, t8);
    }
    {
        int t8x = TT * NB * (DIN / 8);
        conv_x_v<<<(t8x + 255) / 256, 256, 0, stream>>>(enc_in, xbf, t8x);
    }
    for (int l = 0; l < 3; l++)
        conv_bias<<<(4 * NPAD + 255) / 256, 256, 0, stream>>>(b_ih[l], b_hh[l], bias_c[l]);

    for (int l = 0; l < 3; l++) {
        if (l == 0)
            input_gemm<<<3136, 256, 0, stream>>>(xbf, DIN, DIN / 64, Wih_c[0], DIN,
                                                 bias_c[0], pre2);
        else
            input_gemm<<<3136, 256, 0, stream>>>(hall[l - 1], NPAD, NPAD / 64, Wih_c[l], NPAD,
                                                 bias_c[l], pre2);
        rec_persist<<<256, 512, 0, stream>>>(
            Whh_c[l], pre2, hall[l], out + (size_t)l * NB * TT * HID_,
            flags + (size_t)l * 8 * TT);
    }
}

// Round 15
// 1056.212 us; speedup vs baseline: 1.0657x; 1.0212x over previous
//
#include <hip/hip_runtime.h>

#define HID_ 1000
#define NB 256
#define TT 49
#define DIN 192
#define NPAD 1024
#define M_ALL (TT * 256)  // 12544

typedef _Float16 f16;
typedef _Float16 f16x4 __attribute__((ext_vector_type(4)));
typedef _Float16 f16x8 __attribute__((ext_vector_type(8)));
typedef float f32x4 __attribute__((ext_vector_type(4)));
typedef float f32x16 __attribute__((ext_vector_type(16)));
typedef const __attribute__((address_space(1))) unsigned int* gas_u32;
typedef __attribute__((address_space(3))) unsigned int* las_u32;

__device__ __forceinline__ float sigmf_(float x) {
    return 1.0f / (1.0f + __expf(-x));
}
__device__ __forceinline__ float tanhf_(float x) {
    float ax = fabsf(x);
    float e = __expf(-2.0f * ax);
    float t = (1.0f - e) / (1.0f + e);
    return copysignf(t, x);
}

// Vectorized weight convert: fp32 [4*HID_][K] -> f16 [4][1024][KPADv], zero-pad.
__global__ __launch_bounds__(256) void conv_weight_v(
    const float* __restrict__ src, f16* __restrict__ dst, int K, int KPADv, int total8) {
    int idx = blockIdx.x * blockDim.x + threadIdx.x;
    if (idx >= total8) return;
    const int kpw = KPADv >> 3;
    const int kp = (idx % kpw) << 3;
    const int rest = idx / kpw;          // g*1024 + np
    const int np = rest & 1023;
    const int g = rest >> 10;
    f16x8 v = {};
    if (np < HID_ && kp < K) {
        const float* sp = src + (size_t)(g * HID_ + np) * K + kp;
        float4 a = *(const float4*)sp;
        float4 b = *(const float4*)(sp + 4);
        v[0] = (f16)a.x; v[1] = (f16)a.y; v[2] = (f16)a.z; v[3] = (f16)a.w;
        v[4] = (f16)b.x; v[5] = (f16)b.y; v[6] = (f16)b.z; v[7] = (f16)b.w;
    }
    *(f16x8*)(dst + (size_t)rest * KPADv + kp) = v;
}

// Vectorized enc_in transpose-convert: [B][T][D] fp32 -> [T][B][D] f16.
__global__ __launch_bounds__(256) void conv_x_v(
    const float* __restrict__ src, f16* __restrict__ dst, int total8) {
    int idx = blockIdx.x * blockDim.x + threadIdx.x;
    if (idx >= total8) return;
    const int kp = (idx % (DIN / 8)) << 3;
    const int rest = idx / (DIN / 8);    // t*NB + b
    const int b = rest & 255;
    const int t = rest >> 8;
    const float* sp = src + ((size_t)b * TT + t) * DIN + kp;
    float4 a = *(const float4*)sp;
    float4 c = *(const float4*)(sp + 4);
    f16x8 v;
    v[0] = (f16)a.x; v[1] = (f16)a.y; v[2] = (f16)a.z; v[3] = (f16)a.w;
    v[4] = (f16)c.x; v[5] = (f16)c.y; v[6] = (f16)c.z; v[7] = (f16)c.w;
    *(f16x8*)(dst + (size_t)rest * DIN + kp) = v;
}

// bias_c[4][NPAD] fp32 = b_ih + b_hh (zero-padded)
__global__ void conv_bias(const float* __restrict__ bih, const float* __restrict__ bhh,
                          float* __restrict__ dst) {
    int idx = blockIdx.x * blockDim.x + threadIdx.x;
    if (idx < 4 * NPAD) {
        int np = idx & (NPAD - 1);
        int g = idx >> 10;
        float v = 0.0f;
        if (np < HID_) v = bih[g * HID_ + np] + bhh[g * HID_ + np];
        dst[idx] = v;
    }
}

// Pipelined GEMM: pre2 = A @ W^T + bias, 256x256 tile, BK=32, 4-buf LDS
// rotation, counted vmcnt (never 0 in steady state), raw barriers, setprio.
// Stage kt+2 during kt's phases: region being overwritten held kt-2, read 4
// phases ago (barrier-separated) -> safe. vmcnt(4) at each K-tile end
// guarantees kt+1 landed (exactly kt+2's 4 ops may remain outstanding).
// LDS slot-XOR swizzle (slot ^= row&3) applied source-side for the linear
// global_load_lds dest and on the ds_read address.
// Output scatter in rec's 32x32-fragment order (same math as r14, verified).
// grid = 49*16 = 784 (XCD-swizzled), 512 thr (8 waves: wr=M-half, wc=N-qtr).
__global__ __launch_bounds__(512) void gemm8(
    const f16* __restrict__ A, int lda, int nkt,
    const f16* __restrict__ W, int ldw,
    const float* __restrict__ bias,
    f16* __restrict__ pre2) {
    __shared__ f16 lds[4][2][8192];  // [buf][A=0/B=1][256 rows x 32 k]
    const int id = blockIdx.x;
    const int sw = (id & 7) * (gridDim.x >> 3) + (id >> 3);  // 784 % 8 == 0
    const int mt = sw >> 4;   // 0..48  (= t index: 256 rows == one t)
    const int nt = sw & 15;   // 0..15
    const int m0 = mt << 8, n0 = nt << 8;
    const int tid = threadIdx.x;
    const int w = tid >> 6, lane = tid & 63;
    const int r = lane & 15, u = lane >> 4;
    const int wr = w >> 2, wc = w & 3;

    // staging: op o covers rows w*32 + o*16 + (lane>>2), phys 16B-slot lane&3
    const int srow = (w << 5) + (lane >> 2);
    const int pslot = lane & 3;

    f32x4 acc[8][4];
#pragma unroll
    for (int mf = 0; mf < 8; mf++)
#pragma unroll
        for (int nf = 0; nf < 4; nf++) acc[mf][nf] = (f32x4){0.f, 0.f, 0.f, 0.f};

    auto STAGE = [&](int kt, int o) {
        const int b = kt & 3;
        const int row = srow + (o << 4);
        const int ls = pslot ^ (row & 3);  // logical slot for this phys slot
        const f16* ga = A + (size_t)(m0 + row) * lda + kt * 32 + ls * 8;
        const f16* gb = W + (size_t)(n0 + row) * ldw + kt * 32 + ls * 8;
        f16* da = &lds[b][0][0] + (w << 10) + (o << 9);  // wave-uniform base
        f16* db = &lds[b][1][0] + (w << 10) + (o << 9);
        __builtin_amdgcn_global_load_lds((gas_u32)ga, (las_u32)da, 16, 0, 0);
        __builtin_amdgcn_global_load_lds((gas_u32)gb, (las_u32)db, 16, 0, 0);
    };
    auto RDA = [&](int b, int fr) -> f16x8 {
        const int row = (wr << 7) + fr * 16 + r;
        return *(const f16x8*)(&lds[b][0][0] + row * 32 + ((u ^ (row & 3)) << 3));
    };
    auto RDB = [&](int b, int nf) -> f16x8 {
        const int row = (wc << 6) + nf * 16 + r;
        return *(const f16x8*)(&lds[b][1][0] + row * 32 + ((u ^ (row & 3)) << 3));
    };

    // prologue: stage kt0 + kt1 (8 ops/thread), wait kt0 (4 may remain)
    STAGE(0, 0); STAGE(0, 1); STAGE(1, 0); STAGE(1, 1);
    asm volatile("s_waitcnt vmcnt(4)" ::: "memory");
    __builtin_amdgcn_s_barrier();
    __builtin_amdgcn_sched_barrier(0);

    for (int kt = 0; kt < nkt; kt++) {
        const int b = kt & 3;
        const bool st = (kt + 2) < nkt;
        f16x8 bv[4], av[4];
        // ---- phase 0: M-half 0 ----
#pragma unroll
        for (int nf = 0; nf < 4; nf++) bv[nf] = RDB(b, nf);
#pragma unroll
        for (int mf = 0; mf < 4; mf++) av[mf] = RDA(b, mf);
        if (st) STAGE(kt + 2, 0);
        __builtin_amdgcn_s_barrier();
        __builtin_amdgcn_s_setprio(1);
#pragma unroll
        for (int mf = 0; mf < 4; mf++)
#pragma unroll
            for (int nf = 0; nf < 4; nf++)
                acc[mf][nf] = __builtin_amdgcn_mfma_f32_16x16x32_f16(
                    av[mf], bv[nf], acc[mf][nf], 0, 0, 0);
        __builtin_amdgcn_s_setprio(0);
        __builtin_amdgcn_s_barrier();
        // ---- phase 1: M-half 1 (B frags reused in regs) ----
#pragma unroll
        for (int mf = 0; mf < 4; mf++) av[mf] = RDA(b, 4 + mf);
        if (st) STAGE(kt + 2, 1);
        __builtin_amdgcn_s_barrier();
        __builtin_amdgcn_s_setprio(1);
#pragma unroll
        for (int mf = 0; mf < 4; mf++)
#pragma unroll
            for (int nf = 0; nf < 4; nf++)
                acc[4 + mf][nf] = __builtin_amdgcn_mfma_f32_16x16x32_f16(
                    av[mf], bv[nf], acc[4 + mf][nf], 0, 0, 0);
        __builtin_amdgcn_s_setprio(0);
        if (st) asm volatile("s_waitcnt vmcnt(4)" ::: "memory");
        else    asm volatile("s_waitcnt vmcnt(0)" ::: "memory");
        __builtin_amdgcn_s_barrier();
        __builtin_amdgcn_sched_barrier(0);
    }

    // epilogue: bias + scatter to rec's 32x32-fragment layout (r14 math)
#pragma unroll
    for (int nf = 0; nf < 4; nf++) {
        const int gcol = n0 + (wc << 6) + nf * 16 + r;
        const float bj = bias[gcol];
        const int g = gcol >> 10;
        const int jt2 = (gcol & 1023) >> 5;
        const int col32 = gcol & 31;
        const int lane2 = col32 + ((u & 1) << 5);
#pragma unroll
        for (int mf = 0; mf < 8; mf++) {
            const int grow = m0 + (wr << 7) + mf * 16 + (u << 2);  // q=0 row
            const int bt2 = (grow >> 5) & 7;
            const int regbase = ((mf & 1) << 3) + ((u >> 1) << 2);
            f16x4 hv;
#pragma unroll
            for (int q = 0; q < 4; q++) hv[q] = (f16)(acc[mf][nf][q] + bj);
            *(f16x4*)(pre2 + ((((size_t)mt * 8 + bt2) * 32 + jt2) * 4 + g) * 1024 +
                      lane2 * 16 + regbase) = hv;
        }
    }
}

// Persistent per-layer recurrent kernel — r14 version verbatim (best: 238us).
__global__ __launch_bounds__(512, 2) void rec_persist(
    const f16* __restrict__ Whh, const f16* __restrict__ pre2,
    f16* __restrict__ hall, float* __restrict__ outl,
    unsigned int* __restrict__ flags) {
    __shared__ __align__(16) char smem[64 * 1024];  // h tile [32 rows][2048B] XOR5-swizzled
    __shared__ float pl[2 * 4 * 32 * 34];           // [kh][gate][row][34] partials
    const int bid = blockIdx.x;
    const int bt = bid & 7;
    const int jt = bid >> 3;
    const int b0 = bt << 5;
    const int jc0 = jt << 5;
    const int tid = threadIdx.x;
    const int w = tid >> 6;
    const int g = w >> 1;
    const int kh = w & 1;
    const int lane = tid & 63;
    const int row = lane & 31;
    const int kg = lane >> 5;

    f16x8 wreg[32];
    {
        const f16* wp = Whh + ((size_t)(g * NPAD + jc0 + row)) * NPAD + (kh << 9) + (kg << 3);
#pragma unroll
        for (int ks = 0; ks < 32; ks++) wreg[ks] = *(const f16x8*)(wp + ks * 16);
    }

    const int eb = tid >> 4;
    const int ej = (tid & 15) << 1;
    float cv[2] = {0.f, 0.f};
    unsigned int* myflags = flags + bt * TT;
    const size_t preblk = ((((size_t)bt) * 32 + jt) * 4 + g) * 1024 + lane * 16;

    auto LOADP = [&](int tindex, f16x8& pa, f16x8& pb) {
        if (kh == 0) {
            const f16* pp = pre2 + (size_t)tindex * 8 * 32 * 4 * 1024 + preblk;
            pa = *(const f16x8*)pp;
            pb = *(const f16x8*)(pp + 8);
        }
    };

    auto STEP = [&](int t, f16x8& pc0, f16x8& pc1, f16x8& pn0, f16x8& pn1) {
        LOADP(t + 1 < TT ? t + 1 : t, pn0, pn1);

        if (t > 0) {
            while (__hip_atomic_load(myflags + (t - 1), __ATOMIC_RELAXED,
                                     __HIP_MEMORY_SCOPE_AGENT) < 32u) {}
            asm volatile("" ::: "memory");
            const f16* hread = hall + (size_t)(t - 1) * NB * NPAD;
#pragma unroll
            for (int i = 0; i < 8; i++) {
                int c = tid + (i << 9);
                int srow = c >> 7;
                int cb = (c & 127) << 4;
                f16x8 v = *(const f16x8*)(hread + (size_t)(b0 + srow) * NPAD + (cb >> 1));
                *(f16x8*)(smem + srow * 2048 + (cb ^ (srow << 4))) = v;
            }
        }
        __syncthreads();  // B1: h tile staged

        f32x16 acc;
#pragma unroll
        for (int reg = 0; reg < 16; reg++)
            acc[reg] = (kh == 0) ? (float)(reg < 8 ? pc0[reg] : pc1[reg - 8]) : 0.f;

        if (t > 0) {
#pragma unroll
            for (int ks = 0; ks < 32; ks++) {
                const int bc = (kh << 10) + ks * 32 + (kg << 4);
                f16x8 a = *(const f16x8*)(smem + row * 2048 + (bc ^ (row << 4)));
                acc = __builtin_amdgcn_mfma_f32_32x32x16_f16(a, wreg[ks], acc, 0, 0, 0);
            }
        }

#pragma unroll
        for (int reg = 0; reg < 16; reg++) {
            const int prow = (reg & 3) + ((reg >> 2) << 3) + (kg << 2);
            pl[((kh * 4 + g) * 32 + prow) * 34 + row] = acc[reg];
        }
        __syncthreads();  // B2: partials ready

        float hvv[2];
        {
            float gv[4][2];
#pragma unroll
            for (int gate = 0; gate < 4; gate++) {
                float2 p0 = *(const float2*)&pl[((0 * 4 + gate) * 32 + eb) * 34 + ej];
                float2 p1 = *(const float2*)&pl[((1 * 4 + gate) * 32 + eb) * 34 + ej];
                gv[gate][0] = p0.x + p1.x;
                gv[gate][1] = p0.y + p1.y;
            }
#pragma unroll
            for (int q = 0; q < 2; q++) {
                float cn = sigmf_(gv[1][q]) * cv[q] + sigmf_(gv[0][q]) * tanhf_(gv[2][q]);
                hvv[q] = sigmf_(gv[3][q]) * tanhf_(cn);
                cv[q] = cn;
            }
        }
        {
            union { f16 h2[2]; unsigned uu; } cvt;
            cvt.h2[0] = (f16)hvv[0];
            cvt.h2[1] = (f16)hvv[1];
            __hip_atomic_store(
                (unsigned*)(hall + ((size_t)t * NB + b0 + eb) * NPAD + jc0 + ej), cvt.uu,
                __ATOMIC_RELAXED, __HIP_MEMORY_SCOPE_AGENT);
        }
        __syncthreads();  // B3: vmcnt drained -> h stores visible; pl reads done
        if (tid == 0)
            __hip_atomic_fetch_add(myflags + t, 1u, __ATOMIC_RELAXED, __HIP_MEMORY_SCOPE_AGENT);
        const int col = jc0 + ej;
        if (col < HID_) {
            *(float2*)(outl + ((size_t)(b0 + eb) * TT + t) * HID_ + col) =
                make_float2(hvv[0], hvv[1]);
        }
    };

    f16x8 pA0 = {}, pA1 = {}, pB0 = {}, pB1 = {};
    LOADP(0, pA0, pA1);
    for (int t = 0; t < TT; t += 2) {
        STEP(t, pA0, pA1, pB0, pB1);
        if (t + 1 < TT) STEP(t + 1, pB0, pB1, pA0, pA1);
    }
}

extern "C" void kernel_launch(void* const* d_in, const int* in_sizes, int n_in,
                              void* d_out, int out_size, void* d_ws, size_t ws_size,
                              hipStream_t stream) {
    const float* enc_in = (const float*)d_in[0];
    const float* W_ih[3] = {(const float*)d_in[1], (const float*)d_in[5], (const float*)d_in[9]};
    const float* W_hh[3] = {(const float*)d_in[2], (const float*)d_in[6], (const float*)d_in[10]};
    const float* b_ih[3] = {(const float*)d_in[3], (const float*)d_in[7], (const float*)d_in[11]};
    const float* b_hh[3] = {(const float*)d_in[4], (const float*)d_in[8], (const float*)d_in[12]};
    float* out = (float*)d_out;

    char* ws = (char*)d_ws;
    size_t off = 0;
    auto alloc = [&](size_t bytes) {
        char* p = ws + off;
        off += (bytes + 255) & ~(size_t)255;
        return p;
    };
    f16* Wih_c[3];
    f16* Whh_c[3];
    Wih_c[0] = (f16*)alloc(4ull * NPAD * DIN * sizeof(f16));
    Whh_c[0] = (f16*)alloc(4ull * NPAD * NPAD * sizeof(f16));
    Wih_c[1] = (f16*)alloc(4ull * NPAD * NPAD * sizeof(f16));
    Whh_c[1] = (f16*)alloc(4ull * NPAD * NPAD * sizeof(f16));
    Wih_c[2] = (f16*)alloc(4ull * NPAD * NPAD * sizeof(f16));
    Whh_c[2] = (f16*)alloc(4ull * NPAD * NPAD * sizeof(f16));
    float* bias_c[3];
    for (int l = 0; l < 3; l++) bias_c[l] = (float*)alloc(4ull * NPAD * sizeof(float));
    f16* xbf = (f16*)alloc((size_t)TT * NB * DIN * sizeof(f16));
    f16* hall[3];
    for (int l = 0; l < 3; l++) hall[l] = (f16*)alloc((size_t)TT * NB * NPAD * sizeof(f16));
    f16* pre2 = (f16*)alloc((size_t)M_ALL * 4096 * sizeof(f16));
    unsigned int* flags = (unsigned int*)alloc(3ull * 8 * TT * sizeof(unsigned int));

    hipMemsetAsync(flags, 0, 3ull * 8 * TT * sizeof(unsigned int), stream);

    {
        int t8_l0 = 4 * NPAD * DIN / 8;
        conv_weight_v<<<(t8_l0 + 255) / 256, 256, 0, stream>>>(W_ih[0], Wih_c[0], DIN, DIN, t8_l0);
        int t8 = 4 * NPAD * NPAD / 8;
        conv_weight_v<<<(t8 + 255) / 256, 256, 0, stream>>>(W_hh[0], Whh_c[0], HID_, NPAD, t8);
        conv_weight_v<<<(t8 + 255) / 256, 256, 0, stream>>>(W_ih[1], Wih_c[1], HID_, NPAD, t8);
        conv_weight_v<<<(t8 + 255) / 256, 256, 0, stream>>>(W_hh[1], Whh_c[1], HID_, NPAD, t8);
        conv_weight_v<<<(t8 + 255) / 256, 256, 0, stream>>>(W_ih[2], Wih_c[2], HID_, NPAD, t8);
        conv_weight_v<<<(t8 + 255) / 256, 256, 0, stream>>>(W_hh[2], Whh_c[2], HID_, NPAD, t8);
    }
    {
        int t8x = TT * NB * (DIN / 8);
        conv_x_v<<<(t8x + 255) / 256, 256, 0, stream>>>(enc_in, xbf, t8x);
    }
    for (int l = 0; l < 3; l++)
        conv_bias<<<(4 * NPAD + 255) / 256, 256, 0, stream>>>(b_ih[l], b_hh[l], bias_c[l]);

    for (int l = 0; l < 3; l++) {
        if (l == 0)
            gemm8<<<784, 512, 0, stream>>>(xbf, DIN, DIN / 32, Wih_c[0], DIN,
                                           bias_c[0], pre2);
        else
            gemm8<<<784, 512, 0, stream>>>(hall[l - 1], NPAD, NPAD / 32, Wih_c[l], NPAD,
                                           bias_c[l], pre2);
        rec_persist<<<256, 512, 0, stream>>>(
            Whh_c[l], pre2, hall[l], out + (size_t)l * NB * TT * HID_,
            flags + (size_t)l * 8 * TT);
    }
}